// Round 9
// baseline (63.988 us; speedup 1.0000x reference)
//
#include <hip/hip_runtime.h>

// ---------------------------------------------------------------------------
// SpaceTimeStepLookTable, round 9: round-8 structure, celldot restructured:
// 8 cells/block x KS3=8 k-slices (4096 floats). Same compulsory HBM bytes,
// half the Wf L2 re-read traffic, deeper load-level parallelism.
//   out[n,c] = sum_slots relu(feat4)·Wf4 + celldot[cell(n)][c] + dir/t + b
//   Wf = Wproj[:, :128] @ W_mlp   (4 x 37888 packed, fp32, per call)
// Packed slot map (slot = kp/4): f0 0..15 | f1 16..143 | time 144..191 |
//   nb 192..245 | pad 246..255 | f2 256..1279.  f3 handled by celldot.
// ---------------------------------------------------------------------------

#define N_PTS 2048
#define KP_TOTAL 37888
#define K_ORIG 37848
#define KS3 8                     // f3 k-slices of 4096 floats
#define CPB 8                     // cells per celldot block
#define FOLD_BLOCKS 592           // 592*64 == 37888 kp columns

// ---------------------------------------------------------------------------
// Kernel 1 (setup): blocks [0,592) fold Wf; block 592 marks unique f3 cells.
// ---------------------------------------------------------------------------
__global__ __launch_bounds__(256) void setup_kernel(
    const float* __restrict__ Wm, const float* __restrict__ Wproj,
    float* __restrict__ Wf, const float* __restrict__ pos,
    int* __restrict__ list, int* __restrict__ count) {

    const int b = blockIdx.x;
    const int tid = threadIdx.x;

    if (b < FOLD_BLOCKS) {
        // ---- fold: Wf[c][kp] = sum_j Wproj[c*132+j] * Wm[j*K_ORIG + k(kp)]
        __shared__ float red[4][64][4];
        const int kpl = tid & 63;
        const int jq  = tid >> 6;              // wave id, uniform in wave
        const int kp  = b * 64 + kpl;
        int k; bool valid = true;
        if (kp < 576)        k = kp;                       // f0+f1
        else if (kp < 768)   k = 37440 + (kp - 576);       // time
        else if (kp < 984)   k = 37632 + (kp - 768);       // nb
        else if (kp < 1024)  { k = 0; valid = false; }     // zero pad
        else if (kp < 5120)  k = 576 + (kp - 1024);        // f2
        else                 k = 4672 + (kp - 5120);       // f3
        float a0 = 0.f, a1 = 0.f, a2 = 0.f, a3 = 0.f;
        if (valid) {
            const float* wk = Wm + k;
            const int j0 = jq * 32;
            #pragma unroll
            for (int jj = 0; jj < 32; ++jj) {
                const int j = j0 + jj;
                const float w = wk[(size_t)j * K_ORIG];
                a0 = fmaf(Wproj[0 * 132 + j], w, a0);
                a1 = fmaf(Wproj[1 * 132 + j], w, a1);
                a2 = fmaf(Wproj[2 * 132 + j], w, a2);
                a3 = fmaf(Wproj[3 * 132 + j], w, a3);
            }
        }
        red[jq][kpl][0] = a0; red[jq][kpl][1] = a1;
        red[jq][kpl][2] = a2; red[jq][kpl][3] = a3;
        __syncthreads();
        const int rkpl = tid >> 2, rch = tid & 3;
        const float s = red[0][rkpl][rch] + red[1][rkpl][rch]
                      + red[2][rkpl][rch] + red[3][rkpl][rch];
        Wf[(size_t)rch * KP_TOTAL + b * 64 + rkpl] = s;
        return;
    }

    // ---- mark: unique f3 cells (single block -> no inter-block races) ----
    __shared__ int flags[4096];
    __shared__ int cnt;
    for (int i = tid; i < 4096; i += 256) flags[i] = 0;
    if (tid == 0) cnt = 0;
    __syncthreads();
    #pragma unroll
    for (int q = 0; q < 8; ++q) {
        const int n = q * 256 + tid;
        const float px = pos[3 * n], py = pos[3 * n + 1], pz = pos[3 * n + 2];
        const int i3 = (int)(px * 15.f), j3 = (int)(py * 15.f), k3 = (int)(pz * 15.f);
        const int cell = (i3 * 16 + j3) * 16 + k3;
        if (atomicExch(&flags[cell], 1) == 0) {
            const int p = atomicAdd(&cnt, 1);
            list[p] = cell;
        }
    }
    __syncthreads();
    if (tid == 0) count[0] = cnt;
}

// ---------------------------------------------------------------------------
// Kernel 2: per-unique-cell f3 dot. grid (KS3=8, 256) x 256.
// Block (ks, yb) handles cells list[8yb..8yb+8), k-slice ks (4096 floats).
// Per kk iteration: 4 Wf float4 (L2, amortized over 8 cells) + 8 row float4
// (HBM, fully coalesced 1 KB/instr/wave). Each unique row read exactly once.
// ---------------------------------------------------------------------------
__global__ __launch_bounds__(256) void celldot_kernel(
    const float* __restrict__ table3, const float* __restrict__ Wf,
    const int* __restrict__ list, const int* __restrict__ count,
    float* __restrict__ cellpart) {

    const int cnt = count[0];
    const int yb = blockIdx.y;
    if (yb * CPB >= cnt) return;
    const int ks = blockIdx.x;
    const int tid = threadIdx.x;

    int cell[CPB]; const float* rowp[CPB];
    #pragma unroll
    for (int j = 0; j < CPB; ++j) {
        const int idx = yb * CPB + j;
        const int safe = (idx < cnt) ? idx : (cnt - 1);
        cell[j] = list[safe];
        rowp[j] = table3 + (size_t)cell[j] * 32768 + ks * 4096;
    }

    const int qoff = 5120 + ks * 4096;
    const float* wf0 = Wf + (size_t)0 * KP_TOTAL + qoff;
    const float* wf1 = Wf + (size_t)1 * KP_TOTAL + qoff;
    const float* wf2 = Wf + (size_t)2 * KP_TOTAL + qoff;
    const float* wf3 = Wf + (size_t)3 * KP_TOTAL + qoff;

    float accv[CPB][4];
    #pragma unroll
    for (int j = 0; j < CPB; ++j)
        #pragma unroll
        for (int c = 0; c < 4; ++c) accv[j][c] = 0.f;

    #pragma unroll
    for (int kk = 0; kk < 4; ++kk) {
        const int off = kk * 1024 + tid * 4;
        const float4 w0 = *(const float4*)(wf0 + off);
        const float4 w1 = *(const float4*)(wf1 + off);
        const float4 w2 = *(const float4*)(wf2 + off);
        const float4 w3 = *(const float4*)(wf3 + off);
        #pragma unroll
        for (int j = 0; j < CPB; ++j) {
            float4 r = *(const float4*)(rowp[j] + off);
            r.x = fmaxf(r.x, 0.f); r.y = fmaxf(r.y, 0.f);
            r.z = fmaxf(r.z, 0.f); r.w = fmaxf(r.w, 0.f);
            accv[j][0] = fmaf(r.x, w0.x, fmaf(r.y, w0.y, fmaf(r.z, w0.z, fmaf(r.w, w0.w, accv[j][0]))));
            accv[j][1] = fmaf(r.x, w1.x, fmaf(r.y, w1.y, fmaf(r.z, w1.z, fmaf(r.w, w1.w, accv[j][1]))));
            accv[j][2] = fmaf(r.x, w2.x, fmaf(r.y, w2.y, fmaf(r.z, w2.z, fmaf(r.w, w2.w, accv[j][2]))));
            accv[j][3] = fmaf(r.x, w3.x, fmaf(r.y, w3.y, fmaf(r.z, w3.z, fmaf(r.w, w3.w, accv[j][3]))));
        }
    }

    // wave reduce (fixed shuffle order -> deterministic), then cross-wave LDS
    #pragma unroll
    for (int s = 1; s < 64; s <<= 1)
        #pragma unroll
        for (int j = 0; j < CPB; ++j)
            #pragma unroll
            for (int c = 0; c < 4; ++c)
                accv[j][c] += __shfl_xor(accv[j][c], s);

    __shared__ float red[4][CPB * 4];
    const int wv = tid >> 6, ln = tid & 63;
    if (ln == 0)
        #pragma unroll
        for (int j = 0; j < CPB; ++j)
            #pragma unroll
            for (int c = 0; c < 4; ++c)
                red[wv][j * 4 + c] = accv[j][c];
    __syncthreads();
    if (tid < CPB * 4) {
        const float s = red[0][tid] + red[1][tid] + red[2][tid] + red[3][tid];
        const int j = tid >> 2, c = tid & 3;
        if (yb * CPB + j < cnt)
            cellpart[((size_t)ks * 4096 + cell[j]) * 4 + c] = s;
    }
}

// ---------------------------------------------------------------------------
// Kernel 3: fused per-point gather + relu + dot + final projection.
// grid 2048 x 256. Thread tid handles slots {tid, 256+tid, ..., 1024+tid};
// slot>=256 is f2 (coalesced float4); slot<256 covers f0/f1/time/nb/pad.
// Wf index = slot*4 for ALL segments (dense+f2); f3 comes from cellpart.
// ---------------------------------------------------------------------------
__global__ __launch_bounds__(256) void point_kernel(
    const float* __restrict__ pos, const float* __restrict__ dir,
    const float* __restrict__ t,
    const float* __restrict__ table0, const float* __restrict__ table1,
    const float* __restrict__ table2,
    const float* __restrict__ ts1, const float* __restrict__ ts2,
    const float* __restrict__ Wf, const float* __restrict__ cellpart,
    const float* __restrict__ Wproj, const float* __restrict__ bproj,
    float* __restrict__ out) {

    const int n = blockIdx.x;
    const int tid = threadIdx.x;

    const float px = pos[3 * n], py = pos[3 * n + 1], pz = pos[3 * n + 2];
    const float tv = t[n];
    const int i0 = (int)(px * 127.f), j0 = (int)(py * 127.f), k0 = (int)(pz * 127.f);
    const int i1 = (int)(px * 63.f),  j1 = (int)(py * 63.f),  k1 = (int)(pz * 63.f);
    const int i2 = (int)(px * 31.f),  j2 = (int)(py * 31.f),  k2 = (int)(pz * 31.f);
    const int i3 = (int)(px * 15.f),  j3 = (int)(py * 15.f),  k3 = (int)(pz * 15.f);
    const int ti = (int)(tv * 127.f);
    const int cell = (i3 * 16 + j3) * 16 + k3;

    const float* f0p = table0 + (size_t)((i0 * 128 + j0) * 128 + k0) * 64;
    const float* f1p = table1 + (size_t)((i1 * 64 + j1) * 64 + k1) * 512;
    const float* f2p = table2 + (size_t)((i2 * 32 + j2) * 32 + k2) * 4096;
    const float* t1p = ts1 + (size_t)cell * 4096;       // + tw*64 + e

    float a0 = 0.f, a1 = 0.f, a2 = 0.f, a3 = 0.f;

    #pragma unroll
    for (int s5 = 0; s5 < 5; ++s5) {
        const int slot = s5 * 256 + tid;
        float4 f;
        bool have = true;
        if (slot >= 256) {
            f = *(const float4*)(f2p + (slot - 256) * 4);
        } else if (slot < 16) {
            f = *(const float4*)(f0p + slot * 4);
        } else if (slot < 144) {
            f = *(const float4*)(f1p + (slot - 16) * 4);
        } else if (slot < 192) {
            const int s2 = slot - 144;
            const int d = s2 >> 4;
            const int e4 = (s2 & 15) * 4;
            const int tw = (ti + d - 1 + 64) & 63;
            f = *(const float4*)(t1p + tw * 64 + e4);
        } else if (slot < 246) {
            const int o = slot - 192;
            const int dt_ = (o & 1) ? 1 : -1;
            const int rest = o >> 1;
            const int dz_ = rest % 3 - 1;
            const int dy_ = (rest / 3) % 3 - 1;
            const int dx_ = rest / 9 - 1;
            const int x = (i3 + dx_ + 128) & 127;
            const int y = (j3 + dy_ + 128) & 127;
            const int z = (k3 + dz_ + 128) & 127;
            const int w = (ti + dt_ + 128) & 127;
            f = *(const float4*)(ts2 + ((size_t)((x * 128 + y) * 128 + z) * 128 + w) * 4);
        } else {
            have = false;
        }
        if (have) {
            f.x = fmaxf(f.x, 0.f); f.y = fmaxf(f.y, 0.f);
            f.z = fmaxf(f.z, 0.f); f.w = fmaxf(f.w, 0.f);
            const int kp = slot * 4;
            const float4 w0 = *(const float4*)(Wf + (size_t)0 * KP_TOTAL + kp);
            const float4 w1 = *(const float4*)(Wf + (size_t)1 * KP_TOTAL + kp);
            const float4 w2 = *(const float4*)(Wf + (size_t)2 * KP_TOTAL + kp);
            const float4 w3 = *(const float4*)(Wf + (size_t)3 * KP_TOTAL + kp);
            a0 = fmaf(f.x, w0.x, fmaf(f.y, w0.y, fmaf(f.z, w0.z, fmaf(f.w, w0.w, a0))));
            a1 = fmaf(f.x, w1.x, fmaf(f.y, w1.y, fmaf(f.z, w1.z, fmaf(f.w, w1.w, a1))));
            a2 = fmaf(f.x, w2.x, fmaf(f.y, w2.y, fmaf(f.z, w2.z, fmaf(f.w, w2.w, a2))));
            a3 = fmaf(f.x, w3.x, fmaf(f.y, w3.y, fmaf(f.z, w3.z, fmaf(f.w, w3.w, a3))));
        }
    }

    // reduce 256 threads -> 4 channels (fixed order: deterministic)
    #pragma unroll
    for (int s = 1; s < 64; s <<= 1) {
        a0 += __shfl_xor(a0, s);
        a1 += __shfl_xor(a1, s);
        a2 += __shfl_xor(a2, s);
        a3 += __shfl_xor(a3, s);
    }
    __shared__ float red[4][4];
    const int wv = tid >> 6, ln = tid & 63;
    if (ln == 0) { red[wv][0] = a0; red[wv][1] = a1; red[wv][2] = a2; red[wv][3] = a3; }
    __syncthreads();
    if (tid < 4) {
        float s = red[0][tid] + red[1][tid] + red[2][tid] + red[3][tid];
        #pragma unroll
        for (int ks = 0; ks < KS3; ++ks)
            s += cellpart[((size_t)ks * 4096 + cell) * 4 + tid];
        s += dir[3 * n]     * Wproj[tid * 132 + 128];
        s += dir[3 * n + 1] * Wproj[tid * 132 + 129];
        s += dir[3 * n + 2] * Wproj[tid * 132 + 130];
        s += tv             * Wproj[tid * 132 + 131];
        s += bproj[tid];
        out[n * 4 + tid] = s;
    }
}

// ---------------------------------------------------------------------------
extern "C" void kernel_launch(void* const* d_in, const int* in_sizes, int n_in,
                              void* d_out, int out_size, void* d_ws, size_t ws_size,
                              hipStream_t stream) {
    const float* pos    = (const float*)d_in[0];
    const float* dir    = (const float*)d_in[1];
    const float* t      = (const float*)d_in[2];
    const float* table0 = (const float*)d_in[3];
    const float* table1 = (const float*)d_in[4];
    const float* table2 = (const float*)d_in[5];
    const float* table3 = (const float*)d_in[6];
    const float* ts1    = (const float*)d_in[7];
    const float* ts2    = (const float*)d_in[8];
    const float* Wm     = (const float*)d_in[9];
    const float* Wproj  = (const float*)d_in[10];
    const float* bproj  = (const float*)d_in[11];
    float* out = (float*)d_out;

    char* ws = (char*)d_ws;
    float* Wf       = (float*)(ws);                 //   606,208 B
    float* cellpart = (float*)(ws + 606208);        //   524,288 B (8 x 4096 x 4)
    int*   list     = (int*)(ws + 1130496);         //    16,384 B
    int*   count    = (int*)(ws + 1146880);         //        64 B
    // total ws usage: 1,146,944 B

    hipLaunchKernelGGL(setup_kernel, dim3(FOLD_BLOCKS + 1), dim3(256), 0, stream,
                       Wm, Wproj, Wf, pos, list, count);
    hipLaunchKernelGGL(celldot_kernel, dim3(KS3, 256), dim3(256), 0, stream,
                       table3, Wf, list, count, cellpart);
    hipLaunchKernelGGL(point_kernel, dim3(N_PTS), dim3(256), 0, stream,
                       pos, dir, t, table0, table1, table2, ts1, ts2,
                       Wf, cellpart, Wproj, bproj, out);
}

// Round 10
// 60.932 us; speedup vs baseline: 1.0502x; 1.0502x over previous
//
#include <hip/hip_runtime.h>

// ---------------------------------------------------------------------------
// SpaceTimeStepLookTable, round 10: round-9 math, but celldot and the
// per-point gather run CONCURRENTLY in one dispatch ("mega"), so the 211 MB
// f3 stream and the 46 MB point stream share the HBM pipe instead of running
// serially with a launch gap. A tiny final kernel adds cellpart to pointpart.
//   out[n,c] = pointpart[n,c] + sum_ks cellpart[cell(n)][ks][c]
//   pointpart = slots-dot + dir/t/bias;  Wf = Wproj[:,:128] @ W_mlp (packed)
// Packed slot map (slot = kp/4): f0 0..15 | f1 16..143 | time 144..191 |
//   nb 192..245 | pad 246..255 | f2 256..1279.  f3 handled by celldot role.
// ---------------------------------------------------------------------------

#define N_PTS 2048
#define KP_TOTAL 37888
#define K_ORIG 37848
#define KS3 8                     // f3 k-slices of 4096 floats
#define CPB 8                     // cells per celldot block
#define NB_CD 2048                // celldot block slots: (4096/CPB=512 yb)... KS3*256
#define FOLD_BLOCKS 592           // 592*64 == 37888 kp columns

// ---------------------------------------------------------------------------
// Kernel 1 (setup): blocks [0,592) fold Wf; block 592 marks unique f3 cells.
// ---------------------------------------------------------------------------
__global__ __launch_bounds__(256) void setup_kernel(
    const float* __restrict__ Wm, const float* __restrict__ Wproj,
    float* __restrict__ Wf, const float* __restrict__ pos,
    int* __restrict__ list, int* __restrict__ count) {

    const int b = blockIdx.x;
    const int tid = threadIdx.x;

    if (b < FOLD_BLOCKS) {
        // ---- fold: Wf[c][kp] = sum_j Wproj[c*132+j] * Wm[j*K_ORIG + k(kp)]
        __shared__ float red[4][64][4];
        const int kpl = tid & 63;
        const int jq  = tid >> 6;              // wave id, uniform in wave
        const int kp  = b * 64 + kpl;
        int k; bool valid = true;
        if (kp < 576)        k = kp;                       // f0+f1
        else if (kp < 768)   k = 37440 + (kp - 576);       // time
        else if (kp < 984)   k = 37632 + (kp - 768);       // nb
        else if (kp < 1024)  { k = 0; valid = false; }     // zero pad
        else if (kp < 5120)  k = 576 + (kp - 1024);        // f2
        else                 k = 4672 + (kp - 5120);       // f3
        float a0 = 0.f, a1 = 0.f, a2 = 0.f, a3 = 0.f;
        if (valid) {
            const float* wk = Wm + k;
            const int j0 = jq * 32;
            #pragma unroll
            for (int jj = 0; jj < 32; ++jj) {
                const int j = j0 + jj;
                const float w = wk[(size_t)j * K_ORIG];
                a0 = fmaf(Wproj[0 * 132 + j], w, a0);
                a1 = fmaf(Wproj[1 * 132 + j], w, a1);
                a2 = fmaf(Wproj[2 * 132 + j], w, a2);
                a3 = fmaf(Wproj[3 * 132 + j], w, a3);
            }
        }
        red[jq][kpl][0] = a0; red[jq][kpl][1] = a1;
        red[jq][kpl][2] = a2; red[jq][kpl][3] = a3;
        __syncthreads();
        const int rkpl = tid >> 2, rch = tid & 3;
        const float s = red[0][rkpl][rch] + red[1][rkpl][rch]
                      + red[2][rkpl][rch] + red[3][rkpl][rch];
        Wf[(size_t)rch * KP_TOTAL + b * 64 + rkpl] = s;
        return;
    }

    // ---- mark: unique f3 cells (single block -> no inter-block races) ----
    __shared__ int flags[4096];
    __shared__ int cnt;
    for (int i = tid; i < 4096; i += 256) flags[i] = 0;
    if (tid == 0) cnt = 0;
    __syncthreads();
    #pragma unroll
    for (int q = 0; q < 8; ++q) {
        const int n = q * 256 + tid;
        const float px = pos[3 * n], py = pos[3 * n + 1], pz = pos[3 * n + 2];
        const int i3 = (int)(px * 15.f), j3 = (int)(py * 15.f), k3 = (int)(pz * 15.f);
        const int cell = (i3 * 16 + j3) * 16 + k3;
        if (atomicExch(&flags[cell], 1) == 0) {
            const int p = atomicAdd(&cnt, 1);
            list[p] = cell;
        }
    }
    __syncthreads();
    if (tid == 0) count[0] = cnt;
}

// ---------------------------------------------------------------------------
// Kernel 2 (mega): blocks [0, NB_CD) = celldot role (ks = b&7, yb = b>>3);
// blocks [NB_CD, NB_CD + N_PTS) = point role (n = b - NB_CD).
// Roles are independent; both stream from HBM concurrently.
// ---------------------------------------------------------------------------
__global__ __launch_bounds__(256) void mega_kernel(
    const float* __restrict__ table3, const float* __restrict__ Wf,
    const int* __restrict__ list, const int* __restrict__ count,
    float* __restrict__ cellpart,
    const float* __restrict__ pos, const float* __restrict__ dir,
    const float* __restrict__ t,
    const float* __restrict__ table0, const float* __restrict__ table1,
    const float* __restrict__ table2,
    const float* __restrict__ ts1, const float* __restrict__ ts2,
    const float* __restrict__ Wproj, const float* __restrict__ bproj,
    float* __restrict__ pointpart) {

    const int b = blockIdx.x;
    const int tid = threadIdx.x;

    if (b < NB_CD) {
        // ================= celldot role =================
        const int cnt = count[0];
        const int ks = b & 7;
        const int yb = b >> 3;
        if (yb * CPB >= cnt) return;

        int cell[CPB]; const float* rowp[CPB];
        #pragma unroll
        for (int j = 0; j < CPB; ++j) {
            const int idx = yb * CPB + j;
            const int safe = (idx < cnt) ? idx : (cnt - 1);
            cell[j] = list[safe];
            rowp[j] = table3 + (size_t)cell[j] * 32768 + ks * 4096;
        }

        const int qoff = 5120 + ks * 4096;
        const float* wf0 = Wf + (size_t)0 * KP_TOTAL + qoff;
        const float* wf1 = Wf + (size_t)1 * KP_TOTAL + qoff;
        const float* wf2 = Wf + (size_t)2 * KP_TOTAL + qoff;
        const float* wf3 = Wf + (size_t)3 * KP_TOTAL + qoff;

        float accv[CPB][4];
        #pragma unroll
        for (int j = 0; j < CPB; ++j)
            #pragma unroll
            for (int c = 0; c < 4; ++c) accv[j][c] = 0.f;

        #pragma unroll
        for (int kk = 0; kk < 4; ++kk) {
            const int off = kk * 1024 + tid * 4;
            const float4 w0 = *(const float4*)(wf0 + off);
            const float4 w1 = *(const float4*)(wf1 + off);
            const float4 w2 = *(const float4*)(wf2 + off);
            const float4 w3 = *(const float4*)(wf3 + off);
            #pragma unroll
            for (int j = 0; j < CPB; ++j) {
                float4 r = *(const float4*)(rowp[j] + off);
                r.x = fmaxf(r.x, 0.f); r.y = fmaxf(r.y, 0.f);
                r.z = fmaxf(r.z, 0.f); r.w = fmaxf(r.w, 0.f);
                accv[j][0] = fmaf(r.x, w0.x, fmaf(r.y, w0.y, fmaf(r.z, w0.z, fmaf(r.w, w0.w, accv[j][0]))));
                accv[j][1] = fmaf(r.x, w1.x, fmaf(r.y, w1.y, fmaf(r.z, w1.z, fmaf(r.w, w1.w, accv[j][1]))));
                accv[j][2] = fmaf(r.x, w2.x, fmaf(r.y, w2.y, fmaf(r.z, w2.z, fmaf(r.w, w2.w, accv[j][2]))));
                accv[j][3] = fmaf(r.x, w3.x, fmaf(r.y, w3.y, fmaf(r.z, w3.z, fmaf(r.w, w3.w, accv[j][3]))));
            }
        }

        #pragma unroll
        for (int s = 1; s < 64; s <<= 1)
            #pragma unroll
            for (int j = 0; j < CPB; ++j)
                #pragma unroll
                for (int c = 0; c < 4; ++c)
                    accv[j][c] += __shfl_xor(accv[j][c], s);

        __shared__ float redc[4][CPB * 4];
        const int wv = tid >> 6, ln = tid & 63;
        if (ln == 0)
            #pragma unroll
            for (int j = 0; j < CPB; ++j)
                #pragma unroll
                for (int c = 0; c < 4; ++c)
                    redc[wv][j * 4 + c] = accv[j][c];
        __syncthreads();
        if (tid < CPB * 4) {
            const float s = redc[0][tid] + redc[1][tid] + redc[2][tid] + redc[3][tid];
            const int j = tid >> 2, c = tid & 3;
            if (yb * CPB + j < cnt)
                cellpart[((size_t)ks * 4096 + cell[j]) * 4 + c] = s;
        }
        return;
    }

    // ================= point role =================
    const int n = b - NB_CD;

    const float px = pos[3 * n], py = pos[3 * n + 1], pz = pos[3 * n + 2];
    const float tv = t[n];
    const int i0 = (int)(px * 127.f), j0 = (int)(py * 127.f), k0 = (int)(pz * 127.f);
    const int i1 = (int)(px * 63.f),  j1 = (int)(py * 63.f),  k1 = (int)(pz * 63.f);
    const int i2 = (int)(px * 31.f),  j2 = (int)(py * 31.f),  k2 = (int)(pz * 31.f);
    const int i3 = (int)(px * 15.f),  j3 = (int)(py * 15.f),  k3 = (int)(pz * 15.f);
    const int ti = (int)(tv * 127.f);
    const int cell = (i3 * 16 + j3) * 16 + k3;

    const float* f0p = table0 + (size_t)((i0 * 128 + j0) * 128 + k0) * 64;
    const float* f1p = table1 + (size_t)((i1 * 64 + j1) * 64 + k1) * 512;
    const float* f2p = table2 + (size_t)((i2 * 32 + j2) * 32 + k2) * 4096;
    const float* t1p = ts1 + (size_t)cell * 4096;       // + tw*64 + e

    float a0 = 0.f, a1 = 0.f, a2 = 0.f, a3 = 0.f;

    #pragma unroll
    for (int s5 = 0; s5 < 5; ++s5) {
        const int slot = s5 * 256 + tid;
        float4 f;
        bool have = true;
        if (slot >= 256) {
            f = *(const float4*)(f2p + (slot - 256) * 4);
        } else if (slot < 16) {
            f = *(const float4*)(f0p + slot * 4);
        } else if (slot < 144) {
            f = *(const float4*)(f1p + (slot - 16) * 4);
        } else if (slot < 192) {
            const int s2 = slot - 144;
            const int d = s2 >> 4;
            const int e4 = (s2 & 15) * 4;
            const int tw = (ti + d - 1 + 64) & 63;
            f = *(const float4*)(t1p + tw * 64 + e4);
        } else if (slot < 246) {
            const int o = slot - 192;
            const int dt_ = (o & 1) ? 1 : -1;
            const int rest = o >> 1;
            const int dz_ = rest % 3 - 1;
            const int dy_ = (rest / 3) % 3 - 1;
            const int dx_ = rest / 9 - 1;
            const int x = (i3 + dx_ + 128) & 127;
            const int y = (j3 + dy_ + 128) & 127;
            const int z = (k3 + dz_ + 128) & 127;
            const int w = (ti + dt_ + 128) & 127;
            f = *(const float4*)(ts2 + ((size_t)((x * 128 + y) * 128 + z) * 128 + w) * 4);
        } else {
            have = false;
        }
        if (have) {
            f.x = fmaxf(f.x, 0.f); f.y = fmaxf(f.y, 0.f);
            f.z = fmaxf(f.z, 0.f); f.w = fmaxf(f.w, 0.f);
            const int kp = slot * 4;
            const float4 w0 = *(const float4*)(Wf + (size_t)0 * KP_TOTAL + kp);
            const float4 w1 = *(const float4*)(Wf + (size_t)1 * KP_TOTAL + kp);
            const float4 w2 = *(const float4*)(Wf + (size_t)2 * KP_TOTAL + kp);
            const float4 w3 = *(const float4*)(Wf + (size_t)3 * KP_TOTAL + kp);
            a0 = fmaf(f.x, w0.x, fmaf(f.y, w0.y, fmaf(f.z, w0.z, fmaf(f.w, w0.w, a0))));
            a1 = fmaf(f.x, w1.x, fmaf(f.y, w1.y, fmaf(f.z, w1.z, fmaf(f.w, w1.w, a1))));
            a2 = fmaf(f.x, w2.x, fmaf(f.y, w2.y, fmaf(f.z, w2.z, fmaf(f.w, w2.w, a2))));
            a3 = fmaf(f.x, w3.x, fmaf(f.y, w3.y, fmaf(f.z, w3.z, fmaf(f.w, w3.w, a3))));
        }
    }

    #pragma unroll
    for (int s = 1; s < 64; s <<= 1) {
        a0 += __shfl_xor(a0, s);
        a1 += __shfl_xor(a1, s);
        a2 += __shfl_xor(a2, s);
        a3 += __shfl_xor(a3, s);
    }
    __shared__ float redp[4][4];
    const int wv = tid >> 6, ln = tid & 63;
    if (ln == 0) { redp[wv][0] = a0; redp[wv][1] = a1; redp[wv][2] = a2; redp[wv][3] = a3; }
    __syncthreads();
    if (tid < 4) {
        float s = redp[0][tid] + redp[1][tid] + redp[2][tid] + redp[3][tid];
        s += dir[3 * n]     * Wproj[tid * 132 + 128];
        s += dir[3 * n + 1] * Wproj[tid * 132 + 129];
        s += dir[3 * n + 2] * Wproj[tid * 132 + 130];
        s += tv             * Wproj[tid * 132 + 131];
        s += bproj[tid];
        pointpart[n * 4 + tid] = s;
    }
}

// ---------------------------------------------------------------------------
// Kernel 3 (final): out[n,c] = pointpart[n,c] + sum_ks cellpart[cell(n)][c].
// grid 32 x 256: n = blockIdx*64 + tid>>2, c = tid&3. cell recomputed from pos.
// ---------------------------------------------------------------------------
__global__ __launch_bounds__(256) void final_kernel(
    const float* __restrict__ pointpart, const float* __restrict__ cellpart,
    const float* __restrict__ pos, float* __restrict__ out) {
    const int tid = threadIdx.x;
    const int n = blockIdx.x * 64 + (tid >> 2);
    const int c = tid & 3;
    const float px = pos[3 * n], py = pos[3 * n + 1], pz = pos[3 * n + 2];
    const int i3 = (int)(px * 15.f), j3 = (int)(py * 15.f), k3 = (int)(pz * 15.f);
    const int cell = (i3 * 16 + j3) * 16 + k3;
    float s = pointpart[n * 4 + c];
    #pragma unroll
    for (int ks = 0; ks < KS3; ++ks)
        s += cellpart[((size_t)ks * 4096 + cell) * 4 + c];
    out[n * 4 + c] = s;
}

// ---------------------------------------------------------------------------
extern "C" void kernel_launch(void* const* d_in, const int* in_sizes, int n_in,
                              void* d_out, int out_size, void* d_ws, size_t ws_size,
                              hipStream_t stream) {
    const float* pos    = (const float*)d_in[0];
    const float* dir    = (const float*)d_in[1];
    const float* t      = (const float*)d_in[2];
    const float* table0 = (const float*)d_in[3];
    const float* table1 = (const float*)d_in[4];
    const float* table2 = (const float*)d_in[5];
    const float* table3 = (const float*)d_in[6];
    const float* ts1    = (const float*)d_in[7];
    const float* ts2    = (const float*)d_in[8];
    const float* Wm     = (const float*)d_in[9];
    const float* Wproj  = (const float*)d_in[10];
    const float* bproj  = (const float*)d_in[11];
    float* out = (float*)d_out;

    char* ws = (char*)d_ws;
    float* Wf        = (float*)(ws);                 //   606,208 B
    float* cellpart  = (float*)(ws + 606208);        //   524,288 B (8 x 4096 x 4)
    int*   list      = (int*)(ws + 1130496);         //    16,384 B
    int*   count     = (int*)(ws + 1146880);         //        64 B
    float* pointpart = (float*)(ws + 1146944);       //    32,768 B (2048 x 4)
    // total ws usage: 1,179,712 B

    hipLaunchKernelGGL(setup_kernel, dim3(FOLD_BLOCKS + 1), dim3(256), 0, stream,
                       Wm, Wproj, Wf, pos, list, count);
    hipLaunchKernelGGL(mega_kernel, dim3(NB_CD + N_PTS), dim3(256), 0, stream,
                       table3, Wf, list, count, cellpart,
                       pos, dir, t, table0, table1, table2, ts1, ts2,
                       Wproj, bproj, pointpart);
    hipLaunchKernelGGL(final_kernel, dim3(32), dim3(256), 0, stream,
                       pointpart, cellpart, pos, out);
}